// Round 1
// baseline (23033.917 us; speedup 1.0000x reference)
//
#include <hip/hip_runtime.h>
#include <hip/hip_bf16.h>
#include <hip/hip_cooperative_groups.h>

namespace cg = cooperative_groups;

#define SEQ 512
#define BATCH 128
#define INP 512
#define HID 1024
#define CLASSES 1000
#define KTOT (INP + HID)      // 1536

#define NBLK 256
#define NTHR 512
#define BJ 4                  // h-columns per block
#define BN 16                 // gate-cols per block (4 gates x BJ)
#define KP (KTOT + 8)         // padded LDS K-stride (bf16 elems) -> 2-way bank alias only

typedef float f32x4 __attribute__((ext_vector_type(4)));
typedef short bf16x8 __attribute__((ext_vector_type(8)));

__device__ __forceinline__ short f2bf16s(float f) {
    __hip_bfloat16 h = __float2bfloat16(f);   // RNE; compiler emits v_cvt_pk_bf16_f32 pairs
    return __builtin_bit_cast(short, h);
}
__device__ __forceinline__ float bf2f(unsigned short h) {
    union { unsigned u; float f; } v; v.u = ((unsigned)h) << 16;
    return v.f;
}
__device__ __forceinline__ float sigmoidf_(float x) {
    return 1.0f / (1.0f + __expf(-x));
}
__device__ __forceinline__ float tanhf_(float x) {
    x = fminf(fmaxf(x, -15.0f), 15.0f);       // avoid inf/inf
    float e = __expf(2.0f * x);
    return (e - 1.0f) / (e + 1.0f);
}

__global__ __launch_bounds__(NTHR)
void lstm_fused(const float* __restrict__ x,
                const float* __restrict__ W_ih,
                const float* __restrict__ W_hh,
                const float* __restrict__ b_ih,
                const float* __restrict__ b_hh,
                const float* __restrict__ W_fc,
                const float* __restrict__ b_fc,
                float* __restrict__ out,
                unsigned short* __restrict__ h0,
                unsigned short* __restrict__ h1)
{
    __shared__ short W_lds[BN][KP];          // 16 x 1544 x 2B = 49408 B
    __shared__ float gates[BATCH][BN];       // 8192 B
    __shared__ float c_s[BATCH][BJ];         // 2048 B
    __shared__ float bias_s[BN];             // 64 B

    const int tid = threadIdx.x;
    const int bid = blockIdx.x;
    const int j0 = bid * BJ;

    // ---- one-time init: weight slice -> LDS (bf16), bias, zero c, zero h0 ----
    for (int n = 0; n < BN; n++) {
        const int r = (n >> 2) * HID + j0 + (n & 3);   // gate row in [0,4096)
        for (int kk = tid; kk < KTOT; kk += NTHR) {
            float w = (kk < INP) ? W_ih[(size_t)r * INP + kk]
                                 : W_hh[(size_t)r * HID + (kk - INP)];
            W_lds[n][kk] = f2bf16s(w);
        }
    }
    if (tid < BN) {
        const int n = tid;
        const int r = (n >> 2) * HID + j0 + (n & 3);
        bias_s[n] = b_ih[r] + b_hh[r];
    }
    if (tid < BATCH * BJ / 1) { /* 512 == NTHR */ }
    {
        const int i = tid;            // BATCH*BJ == 512 == NTHR
        c_s[i >> 2][i & 3] = 0.0f;
    }
    {   // zero h0 across the grid: 128*1024 bf16 = 65536 dwords
        const unsigned g = (unsigned)bid * NTHR + tid;     // 0..131071
        if (g < (BATCH * HID) / 2) ((unsigned*)h0)[g] = 0u;
    }
    __syncthreads();
    cg::this_grid().sync();

    const int wave = tid >> 6;          // 0..7 -> M-tile
    const int lane = tid & 63;
    const int ln15 = lane & 15;
    const int lgrp = lane >> 4;         // 0..3
    const int arow = wave * 16 + ln15;  // batch row for A fragment
    const int k8 = lgrp * 8;

    for (int t = 0; t < SEQ; t++) {
        const unsigned short* __restrict__ hp = (t & 1) ? h1 : h0;
        unsigned short* __restrict__ hc       = (t & 1) ? h0 : h1;

        f32x4 acc = {0.f, 0.f, 0.f, 0.f};

        // ---- x part: 16 k-tiles (K = 0..511), fp32 load -> bf16 cvt ----
        const float* xt = x + (size_t)t * BATCH * INP + (size_t)arow * INP;
        #pragma unroll
        for (int kt = 0; kt < INP / 32; kt++) {
            const int k0 = kt * 32 + k8;
            const float4 xa = *(const float4*)(xt + k0);
            const float4 xb = *(const float4*)(xt + k0 + 4);
            bf16x8 a;
            a[0] = f2bf16s(xa.x); a[1] = f2bf16s(xa.y);
            a[2] = f2bf16s(xa.z); a[3] = f2bf16s(xa.w);
            a[4] = f2bf16s(xb.x); a[5] = f2bf16s(xb.y);
            a[6] = f2bf16s(xb.z); a[7] = f2bf16s(xb.w);
            bf16x8 b = *(const bf16x8*)&W_lds[ln15][k0];
            acc = __builtin_amdgcn_mfma_f32_16x16x32_bf16(a, b, acc, 0, 0, 0);
        }
        // ---- h part: 32 k-tiles (K = 512..1535), bf16 direct ----
        const unsigned short* hrow = hp + (size_t)arow * HID;
        #pragma unroll
        for (int kt = 0; kt < HID / 32; kt++) {
            const int k0 = kt * 32 + k8;
            bf16x8 a = *(const bf16x8*)(hrow + k0);
            bf16x8 b = *(const bf16x8*)&W_lds[ln15][INP + k0];
            acc = __builtin_amdgcn_mfma_f32_16x16x32_bf16(a, b, acc, 0, 0, 0);
        }

        // ---- scatter gates to LDS (C/D layout: col=lane&15, row=(lane>>4)*4+reg) ----
        {
            const int m0 = wave * 16 + lgrp * 4;
            #pragma unroll
            for (int r = 0; r < 4; r++) gates[m0 + r][ln15] = acc[r];
        }
        __syncthreads();

        // ---- cell update: one cell per thread (512 cells = 128 b x 4 j) ----
        {
            const int b  = tid >> 2;
            const int dj = tid & 3;
            float ig = gates[b][0  + dj] + bias_s[0  + dj];
            float fg = gates[b][4  + dj] + bias_s[4  + dj];
            float gg = gates[b][8  + dj] + bias_s[8  + dj];
            float og = gates[b][12 + dj] + bias_s[12 + dj];
            ig = sigmoidf_(ig); fg = sigmoidf_(fg);
            gg = tanhf_(gg);    og = sigmoidf_(og);
            float c = fg * c_s[b][dj] + ig * gg;
            c_s[b][dj] = c;
            float h = og * tanhf_(c);
            hc[(size_t)b * HID + j0 + dj] = (unsigned short)f2bf16s(h);
        }
        cg::this_grid().sync();
    }

    // ---- FC epilogue: out[b][cls] = h_last . W_fc[cls] + b_fc[cls]; h_last in h0 ----
    {
        const unsigned idx = (unsigned)bid * NTHR + tid;   // 131072 threads >= 128000
        if (idx < BATCH * CLASSES) {
            const int b   = idx / CLASSES;
            const int cls = idx % CLASSES;
            const unsigned short* hrow = h0 + (size_t)b * HID;
            const float* wrow = W_fc + (size_t)cls * HID;
            float acc = 0.f;
            #pragma unroll 4
            for (int k = 0; k < HID; k += 8) {
                bf16x8 hv = *(const bf16x8*)(hrow + k);
                float4 w0 = *(const float4*)(wrow + k);
                float4 w1 = *(const float4*)(wrow + k + 4);
                acc += bf2f((unsigned short)hv[0]) * w0.x
                     + bf2f((unsigned short)hv[1]) * w0.y
                     + bf2f((unsigned short)hv[2]) * w0.z
                     + bf2f((unsigned short)hv[3]) * w0.w
                     + bf2f((unsigned short)hv[4]) * w1.x
                     + bf2f((unsigned short)hv[5]) * w1.y
                     + bf2f((unsigned short)hv[6]) * w1.z
                     + bf2f((unsigned short)hv[7]) * w1.w;
            }
            out[idx] = acc + b_fc[cls];
        }
    }
}

extern "C" void kernel_launch(void* const* d_in, const int* in_sizes, int n_in,
                              void* d_out, int out_size, void* d_ws, size_t ws_size,
                              hipStream_t stream) {
    const float* x    = (const float*)d_in[0];
    const float* W_ih = (const float*)d_in[1];
    const float* W_hh = (const float*)d_in[2];
    const float* b_ih = (const float*)d_in[3];
    const float* b_hh = (const float*)d_in[4];
    const float* W_fc = (const float*)d_in[5];
    const float* b_fc = (const float*)d_in[6];
    float* out = (float*)d_out;

    unsigned short* h0 = (unsigned short*)d_ws;
    unsigned short* h1 = h0 + (size_t)BATCH * HID;

    void* args[] = {&x, &W_ih, &W_hh, &b_ih, &b_hh, &W_fc, &b_fc, &out, &h0, &h1};
    hipLaunchCooperativeKernel((void*)lstm_fused, dim3(NBLK), dim3(NTHR),
                               args, 0, stream);
}

// Round 2
// 9161.184 us; speedup vs baseline: 2.5143x; 2.5143x over previous
//
#include <hip/hip_runtime.h>
#include <hip/hip_bf16.h>
#include <hip/hip_cooperative_groups.h>

namespace cg = cooperative_groups;

#define SEQ 512
#define BATCH 128
#define INP 512
#define HID 1024
#define CLASSES 1000
#define KTOT (INP + HID)      // 1536

#define NBLK 128
#define NTHR 512
#define BJ 8                  // h-columns per block
#define BN 32                 // gate-rows per block (4 gates x BJ)
#define KP (KTOT + 8)         // 1544: row stride (bf16), 16B-aligned, 2-way bank alias only
#define GNP 33                // gates padded row stride (floats) -> conflict-free

typedef float f32x4 __attribute__((ext_vector_type(4)));
typedef short bf16x8 __attribute__((ext_vector_type(8)));

__device__ __forceinline__ short f2bf16s(float f) {
    __hip_bfloat16 h = __float2bfloat16(f);
    return __builtin_bit_cast(short, h);
}
__device__ __forceinline__ float bf2f(unsigned short h) {
    union { unsigned u; float f; } v; v.u = ((unsigned)h) << 16;
    return v.f;
}
__device__ __forceinline__ float sigmoidf_(float x) {
    return 1.0f / (1.0f + __expf(-x));
}
__device__ __forceinline__ float tanhf_(float x) {
    x = fminf(fmaxf(x, -15.0f), 15.0f);
    float e = __expf(2.0f * x);
    return (e - 1.0f) / (e + 1.0f);
}

// ---- hierarchical grid barrier: 16 groups x 8 blocks -> root -> flag ----
// bar[g*32] group counters (g<16), bar[512] root, bar[544] release flag.
// Monotonic counters (no reset within a call); zeroed at kernel start.
__device__ __forceinline__ void bar_arrive(unsigned* bar, int bid, int t) {
    __builtin_amdgcn_fence(__ATOMIC_RELEASE, "agent");   // publish this block's h writes
    const int g = bid >> 3;
    unsigned old = __hip_atomic_fetch_add(&bar[g * 32], 1u, __ATOMIC_RELAXED,
                                          __HIP_MEMORY_SCOPE_AGENT);
    if (old == (unsigned)(8 * (t + 1) - 1)) {            // last in group
        __builtin_amdgcn_fence(__ATOMIC_ACQUIRE, "agent");
        __builtin_amdgcn_fence(__ATOMIC_RELEASE, "agent");
        unsigned r = __hip_atomic_fetch_add(&bar[512], 1u, __ATOMIC_RELAXED,
                                            __HIP_MEMORY_SCOPE_AGENT);
        if (r == (unsigned)(16 * (t + 1) - 1)) {         // last group
            __builtin_amdgcn_fence(__ATOMIC_ACQUIRE, "agent");
            __hip_atomic_store(&bar[544], (unsigned)(t + 1), __ATOMIC_RELEASE,
                               __HIP_MEMORY_SCOPE_AGENT);
        }
    }
}
__device__ __forceinline__ void bar_wait(unsigned* bar, int want) {
    while (__hip_atomic_load(&bar[544], __ATOMIC_RELAXED,
                             __HIP_MEMORY_SCOPE_AGENT) < (unsigned)want)
        __builtin_amdgcn_s_sleep(1);
    __builtin_amdgcn_fence(__ATOMIC_ACQUIRE, "agent");   // invalidate L1/L2 before h reads
}

__global__ __launch_bounds__(NTHR)
void lstm_fused(const float* __restrict__ x,
                const float* __restrict__ W_ih,
                const float* __restrict__ W_hh,
                const float* __restrict__ b_ih,
                const float* __restrict__ b_hh,
                const float* __restrict__ W_fc,
                const float* __restrict__ b_fc,
                float* __restrict__ out,
                unsigned short* __restrict__ h0,
                unsigned short* __restrict__ h1,
                unsigned short* __restrict__ xbf,
                int use_xbf,
                unsigned* __restrict__ bar)
{
    __shared__ short W_lds[BN][KP];          // 32 x 1544 x 2B = 98816 B
    __shared__ float gates[BATCH][GNP];      // 128 x 33 x 4B = 16896 B
    __shared__ float c_s[BATCH * BJ];        // 4096 B
    __shared__ float bias_s[BN];             // 128 B

    const int tid = threadIdx.x;
    const int bid = blockIdx.x;
    const int j0 = bid * BJ;

    // ---------------- one-time init ----------------
    for (int n = 0; n < BN; n++) {
        const int r = (n >> 3) * HID + j0 + (n & 7);       // gate row in [0,4096)
        for (int kk = tid; kk < KTOT; kk += NTHR) {
            float w = (kk < INP) ? W_ih[(size_t)r * INP + kk]
                                 : W_hh[(size_t)r * HID + (kk - INP)];
            W_lds[n][kk] = f2bf16s(w);
        }
    }
    if (tid < BN) {
        const int r = (tid >> 3) * HID + j0 + (tid & 7);
        bias_s[tid] = b_ih[r] + b_hh[r];
    }
    c_s[tid] = 0.0f;
    c_s[tid + NTHR] = 0.0f;
    {   // zero h0: 128*1024 bf16 = 65536 dwords; 65536 grid threads
        const unsigned g = (unsigned)bid * NTHR + tid;
        ((unsigned*)h0)[g] = 0u;
    }
    if (bid == 0) {                                        // zero barrier state
        for (int i = tid; i < 576; i += NTHR) bar[i] = 0u;
    }
    if (use_xbf) {                                         // x fp32 -> bf16, once
        const size_t total8 = (size_t)SEQ * BATCH * INP / 8;   // 8,388,608 chunks
        for (size_t c = (size_t)bid * NTHR + tid; c < total8;
             c += (size_t)NBLK * NTHR) {
            const float* src = x + c * 8;
            const float4 a = *(const float4*)src;
            const float4 b = *(const float4*)(src + 4);
            bf16x8 v;
            v[0] = f2bf16s(a.x); v[1] = f2bf16s(a.y);
            v[2] = f2bf16s(a.z); v[3] = f2bf16s(a.w);
            v[4] = f2bf16s(b.x); v[5] = f2bf16s(b.y);
            v[6] = f2bf16s(b.z); v[7] = f2bf16s(b.w);
            *(bf16x8*)(xbf + c * 8) = v;
        }
    }
    __syncthreads();
    cg::this_grid().sync();

    // ---------------- recurrent loop ----------------
    const int wave = tid >> 6;          // 0..7 -> M-tile
    const int lane = tid & 63;
    const int ln15 = lane & 15;
    const int lgrp = lane >> 4;         // 0..3
    const int arow = wave * 16 + ln15;  // batch row for A fragment
    const int k8 = lgrp * 8;

    const short* Wr0 = &W_lds[ln15][k8];        // n-col = ln15
    const short* Wr1 = &W_lds[16 + ln15][k8];   // n-col = 16+ln15

    for (int t = 0; t < SEQ; t++) {
        const unsigned short* __restrict__ hp = (t & 1) ? h1 : h0;
        unsigned short* __restrict__ hc       = (t & 1) ? h0 : h1;

        f32x4 acc0 = {0.f, 0.f, 0.f, 0.f};
        f32x4 acc1 = {0.f, 0.f, 0.f, 0.f};

        // ---- x-part (independent of h_t) — overlaps other blocks' arrival ----
        if (use_xbf) {
            const unsigned short* xt =
                xbf + (size_t)t * (BATCH * INP) + (size_t)arow * INP + k8;
            #pragma unroll
            for (int kt = 0; kt < INP / 32; kt++) {
                bf16x8 a  = *(const bf16x8*)(xt + kt * 32);
                bf16x8 b0 = *(const bf16x8*)(Wr0 + kt * 32);
                bf16x8 b1 = *(const bf16x8*)(Wr1 + kt * 32);
                acc0 = __builtin_amdgcn_mfma_f32_16x16x32_bf16(a, b0, acc0, 0, 0, 0);
                acc1 = __builtin_amdgcn_mfma_f32_16x16x32_bf16(a, b1, acc1, 0, 0, 0);
            }
        } else {
            const float* xt =
                x + (size_t)t * (BATCH * INP) + (size_t)arow * INP + k8;
            #pragma unroll
            for (int kt = 0; kt < INP / 32; kt++) {
                const float4 xa = *(const float4*)(xt + kt * 32);
                const float4 xb = *(const float4*)(xt + kt * 32 + 4);
                bf16x8 a;
                a[0] = f2bf16s(xa.x); a[1] = f2bf16s(xa.y);
                a[2] = f2bf16s(xa.z); a[3] = f2bf16s(xa.w);
                a[4] = f2bf16s(xb.x); a[5] = f2bf16s(xb.y);
                a[6] = f2bf16s(xb.z); a[7] = f2bf16s(xb.w);
                bf16x8 b0 = *(const bf16x8*)(Wr0 + kt * 32);
                bf16x8 b1 = *(const bf16x8*)(Wr1 + kt * 32);
                acc0 = __builtin_amdgcn_mfma_f32_16x16x32_bf16(a, b0, acc0, 0, 0, 0);
                acc1 = __builtin_amdgcn_mfma_f32_16x16x32_bf16(a, b1, acc1, 0, 0, 0);
            }
        }

        // ---- wait until h_t is published by all blocks ----
        if (tid == 0) bar_wait(bar, t);
        __syncthreads();

        // ---- h-part ----
        {
            const unsigned short* hr = hp + (size_t)arow * HID + k8;
            #pragma unroll
            for (int kt = 0; kt < HID / 32; kt++) {
                bf16x8 a  = *(const bf16x8*)(hr + kt * 32);
                bf16x8 b0 = *(const bf16x8*)(Wr0 + INP + kt * 32);
                bf16x8 b1 = *(const bf16x8*)(Wr1 + INP + kt * 32);
                acc0 = __builtin_amdgcn_mfma_f32_16x16x32_bf16(a, b0, acc0, 0, 0, 0);
                acc1 = __builtin_amdgcn_mfma_f32_16x16x32_bf16(a, b1, acc1, 0, 0, 0);
            }
        }

        // ---- scatter gates (C/D: col=lane&15, row=(lane>>4)*4+reg) ----
        {
            const int m0 = wave * 16 + lgrp * 4;
            #pragma unroll
            for (int r = 0; r < 4; r++) {
                gates[m0 + r][ln15]      = acc0[r];
                gates[m0 + r][16 + ln15] = acc1[r];
            }
        }
        __syncthreads();

        // ---- cell update: 1024 cells, 2 per thread ----
        #pragma unroll
        for (int i = 0; i < 2; i++) {
            const int cell = tid + i * NTHR;
            const int b  = cell >> 3;
            const int dj = cell & 7;
            float ig = gates[b][dj]      + bias_s[dj];
            float fg = gates[b][8 + dj]  + bias_s[8 + dj];
            float gg = gates[b][16 + dj] + bias_s[16 + dj];
            float og = gates[b][24 + dj] + bias_s[24 + dj];
            ig = sigmoidf_(ig); fg = sigmoidf_(fg);
            gg = tanhf_(gg);    og = sigmoidf_(og);
            float c = fg * c_s[cell] + ig * gg;
            c_s[cell] = c;
            float h = og * tanhf_(c);
            hc[(size_t)b * HID + j0 + dj] = (unsigned short)f2bf16s(h);
        }
        __syncthreads();                 // drain hc stores (vmcnt0 before barrier)

        if (tid == 0) bar_arrive(bar, bid, t);
    }

    // all blocks done (and h0 holds h_last since SEQ even); full fence via cg
    cg::this_grid().sync();

    // ---- FC epilogue: 128000 outputs over 65536 threads (2 iters) ----
    for (unsigned idx = (unsigned)bid * NTHR + tid; idx < BATCH * CLASSES;
         idx += (unsigned)NBLK * NTHR) {
        const int b   = idx / CLASSES;
        const int cls = idx % CLASSES;
        const unsigned short* hrow = h0 + (size_t)b * HID;
        const float* wrow = W_fc + (size_t)cls * HID;
        float acc = 0.f;
        #pragma unroll 4
        for (int k = 0; k < HID; k += 8) {
            bf16x8 hv = *(const bf16x8*)(hrow + k);
            float4 w0 = *(const float4*)(wrow + k);
            float4 w1 = *(const float4*)(wrow + k + 4);
            acc += bf2f((unsigned short)hv[0]) * w0.x
                 + bf2f((unsigned short)hv[1]) * w0.y
                 + bf2f((unsigned short)hv[2]) * w0.z
                 + bf2f((unsigned short)hv[3]) * w0.w
                 + bf2f((unsigned short)hv[4]) * w1.x
                 + bf2f((unsigned short)hv[5]) * w1.y
                 + bf2f((unsigned short)hv[6]) * w1.z
                 + bf2f((unsigned short)hv[7]) * w1.w;
        }
        out[idx] = acc + b_fc[cls];
    }
}

extern "C" void kernel_launch(void* const* d_in, const int* in_sizes, int n_in,
                              void* d_out, int out_size, void* d_ws, size_t ws_size,
                              hipStream_t stream) {
    const float* x    = (const float*)d_in[0];
    const float* W_ih = (const float*)d_in[1];
    const float* W_hh = (const float*)d_in[2];
    const float* b_ih = (const float*)d_in[3];
    const float* b_hh = (const float*)d_in[4];
    const float* W_fc = (const float*)d_in[5];
    const float* b_fc = (const float*)d_in[6];
    float* out = (float*)d_out;

    unsigned short* h0 = (unsigned short*)d_ws;                      // 256 KB
    unsigned short* h1 = h0 + (size_t)BATCH * HID;                   // 256 KB
    unsigned short* xbf = (unsigned short*)((char*)d_ws + 524288);   // 64 MB opt
    const size_t need_xbf = 524288 + (size_t)SEQ * BATCH * INP * 2;
    int use_xbf = (ws_size >= need_xbf) ? 1 : 0;
    unsigned* bar = (unsigned*)d_out;   // barrier state; overwritten by FC at end

    void* args[] = {&x, &W_ih, &W_hh, &b_ih, &b_hh, &W_fc, &b_fc,
                    &out, &h0, &h1, &xbf, &use_xbf, &bar};
    hipLaunchCooperativeKernel((void*)lstm_fused, dim3(NBLK), dim3(NTHR),
                               args, 0, stream);
}

// Round 3
// 8112.966 us; speedup vs baseline: 2.8391x; 1.1292x over previous
//
#include <hip/hip_runtime.h>
#include <hip/hip_bf16.h>
#include <hip/hip_cooperative_groups.h>

namespace cg = cooperative_groups;

#define SEQ 512
#define BATCH 128
#define INP 512
#define HID 1024
#define CLASSES 1000
#define KTOT (INP + HID)      // 1536
#define NKT (KTOT / 32)       // 48 k-tiles
#define NKX (INP / 32)        // 16 x k-tiles
#define NKH (HID / 32)        // 32 h k-tiles

#define NBLK 128
#define NTHR 256              // 4 waves, M=32 per wave
#define BJ 8                  // h-columns per block
#define BN 32                 // gate-rows per block (4 gates x BJ)
#define GNP 33                // gates padded row stride (floats)

typedef float f32x4 __attribute__((ext_vector_type(4)));
typedef short bf16x8 __attribute__((ext_vector_type(8)));

__device__ __forceinline__ short f2bf16s(float f) {
    __hip_bfloat16 h = __float2bfloat16(f);
    return __builtin_bit_cast(short, h);
}
__device__ __forceinline__ float sigmoidf_(float x) {
    return 1.0f / (1.0f + __expf(-x));
}
__device__ __forceinline__ float tanhf_(float x) {
    x = fminf(fmaxf(x, -15.0f), 15.0f);
    float e = __expf(2.0f * x);
    return (e - 1.0f) / (e + 1.0f);
}

// ---- hierarchical grid barrier: 16 groups x 8 blocks -> root -> flag ----
// All relaxed atomics (they bypass L2 to the coherent point). No release
// fence needed: h data is written with sc1 write-through atomic stores and
// drained by vmcnt(0) before arrival. Consumer does one acquire fence
// (L1/L2 inv) after the flag flips so NORMAL loads see fresh h from L3.
__device__ __forceinline__ void bar_arrive(unsigned* bar, int bid, int t) {
    const int g = bid >> 3;
    unsigned old = __hip_atomic_fetch_add(&bar[g * 32], 1u, __ATOMIC_RELAXED,
                                          __HIP_MEMORY_SCOPE_AGENT);
    if (old == (unsigned)(8 * (t + 1) - 1)) {            // last in group
        unsigned r = __hip_atomic_fetch_add(&bar[512], 1u, __ATOMIC_RELAXED,
                                            __HIP_MEMORY_SCOPE_AGENT);
        if (r == (unsigned)(16 * (t + 1) - 1)) {         // last group
            __hip_atomic_store(&bar[544], (unsigned)(t + 1), __ATOMIC_RELAXED,
                               __HIP_MEMORY_SCOPE_AGENT);
        }
    }
}
__device__ __forceinline__ void bar_wait(unsigned* bar, int want) {
    while (__hip_atomic_load(&bar[544], __ATOMIC_RELAXED,
                             __HIP_MEMORY_SCOPE_AGENT) < (unsigned)want)
        __builtin_amdgcn_s_sleep(1);
    __builtin_amdgcn_fence(__ATOMIC_ACQUIRE, "agent");   // inv L1/L2 -> read fresh h from L3
}

__global__ __launch_bounds__(NTHR)
void lstm_fused(const float* __restrict__ x,
                const float* __restrict__ W_ih,
                const float* __restrict__ W_hh,
                const float* __restrict__ b_ih,
                const float* __restrict__ b_hh,
                const float* __restrict__ W_fc,
                const float* __restrict__ b_fc,
                float* __restrict__ out,
                unsigned short* __restrict__ h0,
                unsigned short* __restrict__ h1,
                unsigned short* __restrict__ xbf,
                int use_xbf,
                unsigned* __restrict__ bar)
{
    // W in MFMA-fragment order: [nt][kt][lane][8] -> wave B-read is 64
    // lanes x contiguous 16B = conflict-free sequential 1 KiB.
    __shared__ short W_sw[2 * NKT * 64 * 8];   // 98304 B
    __shared__ float gates[BATCH][GNP];        // 16896 B
    __shared__ float c_s[BATCH * BJ];          // 4096 B
    __shared__ float bias_s[BN];               // 128 B

    const int tid = threadIdx.x;
    const int bid = blockIdx.x;
    const int j0 = bid * BJ;

    // ---------------- one-time init ----------------
    // weight slice -> LDS in fragment order (bf16)
    for (int f = tid; f < 2 * NKT * 64; f += NTHR) {    // 24 iters
        const int lane = f & 63;
        const int kt = (f >> 6) % NKT;
        const int nt = f / (NKT * 64);
        const int n = nt * 16 + (lane & 15);            // block n-index 0..31
        const int r = (n >> 3) * HID + j0 + (n & 7);    // global gate row
        const int kbase = kt * 32 + (lane >> 4) * 8;
        short tmp[8];
        #pragma unroll
        for (int j = 0; j < 8; j++) {
            const int k = kbase + j;
            float w = (k < INP) ? W_ih[(size_t)r * INP + k]
                                : W_hh[(size_t)r * HID + (k - INP)];
            tmp[j] = f2bf16s(w);
        }
        *(bf16x8*)&W_sw[(size_t)f * 8] = *(bf16x8*)tmp;
    }
    if (tid < BN) {
        const int r = (tid >> 3) * HID + j0 + (tid & 7);
        bias_s[tid] = b_ih[r] + b_hh[r];
    }
    #pragma unroll
    for (int i = 0; i < 4; i++) c_s[tid + i * NTHR] = 0.0f;
    {   // zero h0: 65536 dwords over 32768 grid threads
        const unsigned g = (unsigned)bid * NTHR + tid;
        ((unsigned*)h0)[g] = 0u;
        ((unsigned*)h0)[g + (unsigned)NBLK * NTHR] = 0u;
    }
    if (bid == 0) {
        for (int i = tid; i < 576; i += NTHR) bar[i] = 0u;
    }
    if (use_xbf) {                                      // x fp32 -> bf16 once
        const size_t total8 = (size_t)SEQ * BATCH * INP / 8;
        for (size_t c = (size_t)bid * NTHR + tid; c < total8;
             c += (size_t)NBLK * NTHR) {
            const float* src = x + c * 8;
            const float4 a = *(const float4*)src;
            const float4 b = *(const float4*)(src + 4);
            bf16x8 v;
            v[0] = f2bf16s(a.x); v[1] = f2bf16s(a.y);
            v[2] = f2bf16s(a.z); v[3] = f2bf16s(a.w);
            v[4] = f2bf16s(b.x); v[5] = f2bf16s(b.y);
            v[6] = f2bf16s(b.z); v[7] = f2bf16s(b.w);
            *(bf16x8*)(xbf + c * 8) = v;
        }
    }
    __syncthreads();
    cg::this_grid().sync();

    // ---------------- recurrent loop ----------------
    const int wave = tid >> 6;          // 0..3 -> M-block of 32 rows
    const int lane = tid & 63;
    const int ln15 = lane & 15;
    const int lgrp = lane >> 4;         // 0..3
    const int arow0 = wave * 32 + ln15; // first M-tile batch row
    const int k8 = lgrp * 8;

    const bf16x8* Wl = (const bf16x8*)W_sw + lane;     // + (nt*NKT + kt)*64

    for (int t = 0; t < SEQ; t++) {
        const unsigned short* __restrict__ hp = (t & 1) ? h1 : h0;
        unsigned short* __restrict__ hc       = (t & 1) ? h0 : h1;

        f32x4 acc00 = {0.f,0.f,0.f,0.f}, acc01 = {0.f,0.f,0.f,0.f};
        f32x4 acc10 = {0.f,0.f,0.f,0.f}, acc11 = {0.f,0.f,0.f,0.f};

        // ---- x-part (independent of h_t): overlaps other blocks' arrival ----
        if (use_xbf) {
            const unsigned short* xr0 =
                xbf + (size_t)t * (BATCH * INP) + (size_t)arow0 * INP + k8;
            const unsigned short* xr1 = xr0 + 16 * INP;
            #pragma unroll
            for (int kt = 0; kt < NKX; kt++) {
                bf16x8 a0 = *(const bf16x8*)(xr0 + kt * 32);
                bf16x8 a1 = *(const bf16x8*)(xr1 + kt * 32);
                bf16x8 b0 = Wl[kt * 64];
                bf16x8 b1 = Wl[(NKT + kt) * 64];
                acc00 = __builtin_amdgcn_mfma_f32_16x16x32_bf16(a0, b0, acc00, 0, 0, 0);
                acc01 = __builtin_amdgcn_mfma_f32_16x16x32_bf16(a0, b1, acc01, 0, 0, 0);
                acc10 = __builtin_amdgcn_mfma_f32_16x16x32_bf16(a1, b0, acc10, 0, 0, 0);
                acc11 = __builtin_amdgcn_mfma_f32_16x16x32_bf16(a1, b1, acc11, 0, 0, 0);
            }
        } else {
            const float* xr0 =
                x + (size_t)t * (BATCH * INP) + (size_t)arow0 * INP + k8;
            const float* xr1 = xr0 + 16 * INP;
            #pragma unroll
            for (int kt = 0; kt < NKX; kt++) {
                const float4 xa = *(const float4*)(xr0 + kt * 32);
                const float4 xb = *(const float4*)(xr0 + kt * 32 + 4);
                const float4 ya = *(const float4*)(xr1 + kt * 32);
                const float4 yb = *(const float4*)(xr1 + kt * 32 + 4);
                bf16x8 a0, a1;
                a0[0]=f2bf16s(xa.x); a0[1]=f2bf16s(xa.y); a0[2]=f2bf16s(xa.z); a0[3]=f2bf16s(xa.w);
                a0[4]=f2bf16s(xb.x); a0[5]=f2bf16s(xb.y); a0[6]=f2bf16s(xb.z); a0[7]=f2bf16s(xb.w);
                a1[0]=f2bf16s(ya.x); a1[1]=f2bf16s(ya.y); a1[2]=f2bf16s(ya.z); a1[3]=f2bf16s(ya.w);
                a1[4]=f2bf16s(yb.x); a1[5]=f2bf16s(yb.y); a1[6]=f2bf16s(yb.z); a1[7]=f2bf16s(yb.w);
                bf16x8 b0 = Wl[kt * 64];
                bf16x8 b1 = Wl[(NKT + kt) * 64];
                acc00 = __builtin_amdgcn_mfma_f32_16x16x32_bf16(a0, b0, acc00, 0, 0, 0);
                acc01 = __builtin_amdgcn_mfma_f32_16x16x32_bf16(a0, b1, acc01, 0, 0, 0);
                acc10 = __builtin_amdgcn_mfma_f32_16x16x32_bf16(a1, b0, acc10, 0, 0, 0);
                acc11 = __builtin_amdgcn_mfma_f32_16x16x32_bf16(a1, b1, acc11, 0, 0, 0);
            }
        }

        // ---- wait for h_t; acquire-inv so normal loads see fresh data ----
        if (tid == 0) bar_wait(bar, t);
        __syncthreads();

        // ---- h-part: normal pipelined loads (hit L3 after inv) ----
        {
            const unsigned short* hr0 = hp + (size_t)arow0 * HID + k8;
            const unsigned short* hr1 = hr0 + 16 * HID;
            #pragma unroll
            for (int kt = 0; kt < NKH; kt++) {
                bf16x8 a0 = *(const bf16x8*)(hr0 + kt * 32);
                bf16x8 a1 = *(const bf16x8*)(hr1 + kt * 32);
                bf16x8 b0 = Wl[(NKX + kt) * 64];
                bf16x8 b1 = Wl[(NKT + NKX + kt) * 64];
                acc00 = __builtin_amdgcn_mfma_f32_16x16x32_bf16(a0, b0, acc00, 0, 0, 0);
                acc01 = __builtin_amdgcn_mfma_f32_16x16x32_bf16(a0, b1, acc01, 0, 0, 0);
                acc10 = __builtin_amdgcn_mfma_f32_16x16x32_bf16(a1, b0, acc10, 0, 0, 0);
                acc11 = __builtin_amdgcn_mfma_f32_16x16x32_bf16(a1, b1, acc11, 0, 0, 0);
            }
        }

        // ---- scatter gates (C/D: col=lane&15, row=(lane>>4)*4+reg) ----
        {
            const int m0 = wave * 32 + lgrp * 4;
            #pragma unroll
            for (int r = 0; r < 4; r++) {
                gates[m0 + r][ln15]           = acc00[r];
                gates[m0 + r][16 + ln15]      = acc01[r];
                gates[m0 + 16 + r][ln15]      = acc10[r];
                gates[m0 + 16 + r][16 + ln15] = acc11[r];
            }
        }
        __syncthreads();

        // ---- cell update: 1024 cells, 4 per thread; packed 8B sc1 store ----
        {
            const int b  = tid >> 1;
            const int jh = (tid & 1) * 4;
            unsigned long long pack = 0;
            #pragma unroll
            for (int c4 = 0; c4 < 4; c4++) {
                const int dj = jh + c4;
                float ig = gates[b][dj]      + bias_s[dj];
                float fg = gates[b][8 + dj]  + bias_s[8 + dj];
                float gg = gates[b][16 + dj] + bias_s[16 + dj];
                float og = gates[b][24 + dj] + bias_s[24 + dj];
                ig = sigmoidf_(ig); fg = sigmoidf_(fg);
                gg = tanhf_(gg);    og = sigmoidf_(og);
                float c = fg * c_s[b * BJ + dj] + ig * gg;
                c_s[b * BJ + dj] = c;
                float h = og * tanhf_(c);
                pack |= ((unsigned long long)(unsigned short)f2bf16s(h)) << (16 * c4);
            }
            // write-through to L3 (agent-coherent point); no fence needed
            __hip_atomic_store((unsigned long long*)(hc + (size_t)b * HID + j0 + jh),
                               pack, __ATOMIC_RELAXED, __HIP_MEMORY_SCOPE_AGENT);
        }
        asm volatile("s_waitcnt vmcnt(0)" ::: "memory");  // h acked at L3
        __syncthreads();

        if (tid == 0) bar_arrive(bar, bid, t);
    }

    // all blocks done; h_last is in h0 (SEQ even). Full fence via cg sync.
    cg::this_grid().sync();

    // ---- FC epilogue: 128000 outputs over 32768 threads (4 iters) ----
    for (unsigned idx = (unsigned)bid * NTHR + tid; idx < BATCH * CLASSES;
         idx += (unsigned)NBLK * NTHR) {
        const int b   = idx / CLASSES;
        const int cls = idx % CLASSES;
        const unsigned short* hrow = h0 + (size_t)b * HID;
        const float* wrow = W_fc + (size_t)cls * HID;
        float acc = 0.f;
        #pragma unroll 4
        for (int k = 0; k < HID; k += 8) {
            bf16x8 hv = *(const bf16x8*)(hrow + k);
            float4 w0 = *(const float4*)(wrow + k);
            float4 w1 = *(const float4*)(wrow + k + 4);
            union { unsigned u; float f; } e;
            float s = 0.f;
            e.u = ((unsigned)(unsigned short)hv[0]) << 16; s += e.f * w0.x;
            e.u = ((unsigned)(unsigned short)hv[1]) << 16; s += e.f * w0.y;
            e.u = ((unsigned)(unsigned short)hv[2]) << 16; s += e.f * w0.z;
            e.u = ((unsigned)(unsigned short)hv[3]) << 16; s += e.f * w0.w;
            e.u = ((unsigned)(unsigned short)hv[4]) << 16; s += e.f * w1.x;
            e.u = ((unsigned)(unsigned short)hv[5]) << 16; s += e.f * w1.y;
            e.u = ((unsigned)(unsigned short)hv[6]) << 16; s += e.f * w1.z;
            e.u = ((unsigned)(unsigned short)hv[7]) << 16; s += e.f * w1.w;
            acc += s;
        }
        out[idx] = acc + b_fc[cls];
    }
}

extern "C" void kernel_launch(void* const* d_in, const int* in_sizes, int n_in,
                              void* d_out, int out_size, void* d_ws, size_t ws_size,
                              hipStream_t stream) {
    const float* x    = (const float*)d_in[0];
    const float* W_ih = (const float*)d_in[1];
    const float* W_hh = (const float*)d_in[2];
    const float* b_ih = (const float*)d_in[3];
    const float* b_hh = (const float*)d_in[4];
    const float* W_fc = (const float*)d_in[5];
    const float* b_fc = (const float*)d_in[6];
    float* out = (float*)d_out;

    unsigned short* h0 = (unsigned short*)d_ws;                      // 256 KB
    unsigned short* h1 = h0 + (size_t)BATCH * HID;                   // 256 KB
    unsigned short* xbf = (unsigned short*)((char*)d_ws + 524288);   // 64 MB opt
    const size_t need_xbf = 524288 + (size_t)SEQ * BATCH * INP * 2;
    int use_xbf = (ws_size >= need_xbf) ? 1 : 0;
    unsigned* bar = (unsigned*)d_out;   // barrier state; overwritten by FC at end

    void* args[] = {&x, &W_ih, &W_hh, &b_ih, &b_hh, &W_fc, &b_fc,
                    &out, &h0, &h1, &xbf, &use_xbf, &bar};
    hipLaunchCooperativeKernel((void*)lstm_fused, dim3(NBLK), dim3(NTHR),
                               args, 0, stream);
}

// Round 4
// 7869.157 us; speedup vs baseline: 2.9271x; 1.0310x over previous
//
#include <hip/hip_runtime.h>
#include <hip/hip_bf16.h>
#include <hip/hip_cooperative_groups.h>

namespace cg = cooperative_groups;

#define SEQ 512
#define BATCH 128
#define INP 512
#define HID 1024
#define CLASSES 1000
#define KTOT (INP + HID)      // 1536
#define NKT (KTOT / 32)       // 48 k-tiles
#define NKX (INP / 32)        // 16 x k-tiles
#define NKH (HID / 32)        // 32 h k-tiles

#define NBLK 128
#define NTHR 256              // 4 waves, M=32 per wave
#define BJ 8                  // h-columns per block
#define BN 32                 // gate-rows per block (4 gates x BJ)
#define GNP 33                // gates padded row stride (floats)

typedef float f32x4 __attribute__((ext_vector_type(4)));
typedef short bf16x8 __attribute__((ext_vector_type(8)));

__device__ __forceinline__ short f2bf16s(float f) {
    __hip_bfloat16 h = __float2bfloat16(f);
    return __builtin_bit_cast(short, h);
}
__device__ __forceinline__ float sigmoidf_(float x) {
    return 1.0f / (1.0f + __expf(-x));
}
__device__ __forceinline__ float tanhf_(float x) {
    x = fminf(fmaxf(x, -15.0f), 15.0f);
    float e = __expf(2.0f * x);
    return (e - 1.0f) / (e + 1.0f);
}

// ---- all-to-all flag barrier: zero serialized RMWs on the critical path ----
// Arrive: ONE relaxed atomic store to flags[bid] (own word; stores to distinct
// words pipeline at the L3 slice — no ownership transfer, no RMW chain).
// Wait: wave 0's 64 lanes poll all 128 flags in parallel (2 loads/lane +
// __all ballot) — one poll iteration = one L3 RTT, not 24 serialized RTTs.
__device__ __forceinline__ void bar_signal(unsigned* flags, int bid, unsigned val) {
    __hip_atomic_store(&flags[bid], val, __ATOMIC_RELAXED,
                       __HIP_MEMORY_SCOPE_AGENT);
}
__device__ __forceinline__ void bar_wait_all(unsigned* flags, int lane, unsigned want) {
    const unsigned* p0 = &flags[lane];
    const unsigned* p1 = &flags[64 + lane];
    for (;;) {
        unsigned f0 = __hip_atomic_load(p0, __ATOMIC_RELAXED,
                                        __HIP_MEMORY_SCOPE_AGENT);
        unsigned f1 = __hip_atomic_load(p1, __ATOMIC_RELAXED,
                                        __HIP_MEMORY_SCOPE_AGENT);
        if (__all((f0 >= want) && (f1 >= want))) break;
        __builtin_amdgcn_s_sleep(1);
    }
    __builtin_amdgcn_fence(__ATOMIC_ACQUIRE, "agent");  // inv L1/L2 -> fresh h from L3
}

__global__ __launch_bounds__(NTHR)
void lstm_fused(const float* __restrict__ x,
                const float* __restrict__ W_ih,
                const float* __restrict__ W_hh,
                const float* __restrict__ b_ih,
                const float* __restrict__ b_hh,
                const float* __restrict__ W_fc,
                const float* __restrict__ b_fc,
                float* __restrict__ out,
                unsigned short* __restrict__ h0,
                unsigned short* __restrict__ h1,
                unsigned short* __restrict__ xbf,
                int use_xbf,
                unsigned* __restrict__ flags)
{
    // W in MFMA-fragment order: [nt][kt][lane][8] -> wave B-read is 64
    // lanes x contiguous 16B = conflict-free sequential 1 KiB.
    __shared__ short W_sw[2 * NKT * 64 * 8];   // 98304 B
    __shared__ float gates[BATCH][GNP];        // 16896 B
    __shared__ float c_s[BATCH * BJ];          // 4096 B
    __shared__ float bias_s[BN];               // 128 B

    const int tid = threadIdx.x;
    const int bid = blockIdx.x;
    const int j0 = bid * BJ;

    // ---------------- one-time init ----------------
    for (int f = tid; f < 2 * NKT * 64; f += NTHR) {    // 24 iters
        const int lane = f & 63;
        const int kt = (f >> 6) % NKT;
        const int nt = f / (NKT * 64);
        const int n = nt * 16 + (lane & 15);            // block n-index 0..31
        const int r = (n >> 3) * HID + j0 + (n & 7);    // global gate row
        const int kbase = kt * 32 + (lane >> 4) * 8;
        short tmp[8];
        #pragma unroll
        for (int j = 0; j < 8; j++) {
            const int k = kbase + j;
            float w = (k < INP) ? W_ih[(size_t)r * INP + k]
                                : W_hh[(size_t)r * HID + (k - INP)];
            tmp[j] = f2bf16s(w);
        }
        *(bf16x8*)&W_sw[(size_t)f * 8] = *(bf16x8*)tmp;
    }
    if (tid < BN) {
        const int r = (tid >> 3) * HID + j0 + (tid & 7);
        bias_s[tid] = b_ih[r] + b_hh[r];
    }
    #pragma unroll
    for (int i = 0; i < 4; i++) c_s[tid + i * NTHR] = 0.0f;
    {   // zero h0: 65536 dwords over 32768 grid threads
        const unsigned g = (unsigned)bid * NTHR + tid;
        ((unsigned*)h0)[g] = 0u;
        ((unsigned*)h0)[g + (unsigned)NBLK * NTHR] = 0u;
    }
    if (bid == 0) {
        for (int i = tid; i < NBLK; i += NTHR) flags[i] = 0u;
    }
    if (use_xbf) {                                      // x fp32 -> bf16 once
        const size_t total8 = (size_t)SEQ * BATCH * INP / 8;
        for (size_t c = (size_t)bid * NTHR + tid; c < total8;
             c += (size_t)NBLK * NTHR) {
            const float* src = x + c * 8;
            const float4 a = *(const float4*)src;
            const float4 b = *(const float4*)(src + 4);
            bf16x8 v;
            v[0] = f2bf16s(a.x); v[1] = f2bf16s(a.y);
            v[2] = f2bf16s(a.z); v[3] = f2bf16s(a.w);
            v[4] = f2bf16s(b.x); v[5] = f2bf16s(b.y);
            v[6] = f2bf16s(b.z); v[7] = f2bf16s(b.w);
            *(bf16x8*)(xbf + c * 8) = v;
        }
    }
    __syncthreads();
    cg::this_grid().sync();

    // ---------------- recurrent loop ----------------
    const int wave = tid >> 6;          // 0..3 -> M-block of 32 rows
    const int lane = tid & 63;
    const int ln15 = lane & 15;
    const int lgrp = lane >> 4;         // 0..3
    const int arow0 = wave * 32 + ln15; // first M-tile batch row
    const int k8 = lgrp * 8;

    const bf16x8* Wl = (const bf16x8*)W_sw + lane;     // + (nt*NKT + kt)*64

    for (int t = 0; t < SEQ; t++) {
        const unsigned short* __restrict__ hp = (t & 1) ? h1 : h0;
        unsigned short* __restrict__ hc       = (t & 1) ? h0 : h1;

        f32x4 acc00 = {0.f,0.f,0.f,0.f}, acc01 = {0.f,0.f,0.f,0.f};
        f32x4 acc10 = {0.f,0.f,0.f,0.f}, acc11 = {0.f,0.f,0.f,0.f};

        // ---- x-part (independent of h_t): overlaps other blocks' arrival ----
        if (use_xbf) {
            const unsigned short* xr0 =
                xbf + (size_t)t * (BATCH * INP) + (size_t)arow0 * INP + k8;
            const unsigned short* xr1 = xr0 + 16 * INP;
            #pragma unroll
            for (int kt = 0; kt < NKX; kt++) {
                bf16x8 a0 = *(const bf16x8*)(xr0 + kt * 32);
                bf16x8 a1 = *(const bf16x8*)(xr1 + kt * 32);
                bf16x8 b0 = Wl[kt * 64];
                bf16x8 b1 = Wl[(NKT + kt) * 64];
                acc00 = __builtin_amdgcn_mfma_f32_16x16x32_bf16(a0, b0, acc00, 0, 0, 0);
                acc01 = __builtin_amdgcn_mfma_f32_16x16x32_bf16(a0, b1, acc01, 0, 0, 0);
                acc10 = __builtin_amdgcn_mfma_f32_16x16x32_bf16(a1, b0, acc10, 0, 0, 0);
                acc11 = __builtin_amdgcn_mfma_f32_16x16x32_bf16(a1, b1, acc11, 0, 0, 0);
            }
        } else {
            const float* xr0 =
                x + (size_t)t * (BATCH * INP) + (size_t)arow0 * INP + k8;
            const float* xr1 = xr0 + 16 * INP;
            #pragma unroll
            for (int kt = 0; kt < NKX; kt++) {
                const float4 xa = *(const float4*)(xr0 + kt * 32);
                const float4 xb = *(const float4*)(xr0 + kt * 32 + 4);
                const float4 ya = *(const float4*)(xr1 + kt * 32);
                const float4 yb = *(const float4*)(xr1 + kt * 32 + 4);
                bf16x8 a0, a1;
                a0[0]=f2bf16s(xa.x); a0[1]=f2bf16s(xa.y); a0[2]=f2bf16s(xa.z); a0[3]=f2bf16s(xa.w);
                a0[4]=f2bf16s(xb.x); a0[5]=f2bf16s(xb.y); a0[6]=f2bf16s(xb.z); a0[7]=f2bf16s(xb.w);
                a1[0]=f2bf16s(ya.x); a1[1]=f2bf16s(ya.y); a1[2]=f2bf16s(ya.z); a1[3]=f2bf16s(ya.w);
                a1[4]=f2bf16s(yb.x); a1[5]=f2bf16s(yb.y); a1[6]=f2bf16s(yb.z); a1[7]=f2bf16s(yb.w);
                bf16x8 b0 = Wl[kt * 64];
                bf16x8 b1 = Wl[(NKT + kt) * 64];
                acc00 = __builtin_amdgcn_mfma_f32_16x16x32_bf16(a0, b0, acc00, 0, 0, 0);
                acc01 = __builtin_amdgcn_mfma_f32_16x16x32_bf16(a0, b1, acc01, 0, 0, 0);
                acc10 = __builtin_amdgcn_mfma_f32_16x16x32_bf16(a1, b0, acc10, 0, 0, 0);
                acc11 = __builtin_amdgcn_mfma_f32_16x16x32_bf16(a1, b1, acc11, 0, 0, 0);
            }
        }

        // ---- wait for h_t (wave0 polls all flags in parallel) ----
        if (tid < 64) bar_wait_all(flags, lane, (unsigned)t);
        __syncthreads();

        // ---- h-part: normal pipelined loads (hit L3 after inv) ----
        {
            const unsigned short* hr0 = hp + (size_t)arow0 * HID + k8;
            const unsigned short* hr1 = hr0 + 16 * HID;
            #pragma unroll
            for (int kt = 0; kt < NKH; kt++) {
                bf16x8 a0 = *(const bf16x8*)(hr0 + kt * 32);
                bf16x8 a1 = *(const bf16x8*)(hr1 + kt * 32);
                bf16x8 b0 = Wl[(NKX + kt) * 64];
                bf16x8 b1 = Wl[(NKT + NKX + kt) * 64];
                acc00 = __builtin_amdgcn_mfma_f32_16x16x32_bf16(a0, b0, acc00, 0, 0, 0);
                acc01 = __builtin_amdgcn_mfma_f32_16x16x32_bf16(a0, b1, acc01, 0, 0, 0);
                acc10 = __builtin_amdgcn_mfma_f32_16x16x32_bf16(a1, b0, acc10, 0, 0, 0);
                acc11 = __builtin_amdgcn_mfma_f32_16x16x32_bf16(a1, b1, acc11, 0, 0, 0);
            }
        }

        // ---- scatter gates (C/D: col=lane&15, row=(lane>>4)*4+reg) ----
        {
            const int m0 = wave * 32 + lgrp * 4;
            #pragma unroll
            for (int r = 0; r < 4; r++) {
                gates[m0 + r][ln15]           = acc00[r];
                gates[m0 + r][16 + ln15]      = acc01[r];
                gates[m0 + 16 + r][ln15]      = acc10[r];
                gates[m0 + 16 + r][16 + ln15] = acc11[r];
            }
        }
        __syncthreads();

        // ---- cell update: 1024 cells, 4 per thread; packed 8B store ----
        {
            const int b  = tid >> 1;
            const int jh = (tid & 1) * 4;
            unsigned long long pack = 0;
            #pragma unroll
            for (int c4 = 0; c4 < 4; c4++) {
                const int dj = jh + c4;
                float ig = gates[b][dj]      + bias_s[dj];
                float fg = gates[b][8 + dj]  + bias_s[8 + dj];
                float gg = gates[b][16 + dj] + bias_s[16 + dj];
                float og = gates[b][24 + dj] + bias_s[24 + dj];
                ig = sigmoidf_(ig); fg = sigmoidf_(fg);
                gg = tanhf_(gg);    og = sigmoidf_(og);
                float c = fg * c_s[b * BJ + dj] + ig * gg;
                c_s[b * BJ + dj] = c;
                float h = og * tanhf_(c);
                pack |= ((unsigned long long)(unsigned short)f2bf16s(h)) << (16 * c4);
            }
            // write-through to L3 (agent-coherent point)
            __hip_atomic_store((unsigned long long*)(hc + (size_t)b * HID + j0 + jh),
                               pack, __ATOMIC_RELAXED, __HIP_MEMORY_SCOPE_AGENT);
        }
        asm volatile("s_waitcnt vmcnt(0)" ::: "memory");  // h acked at L3
        __syncthreads();                                   // all waves' h acked

        if (tid == 0) bar_signal(flags, bid, (unsigned)(t + 1));
    }

    // all blocks done; h_last is in h0 (SEQ even). Full fence via cg sync.
    cg::this_grid().sync();

    // ---- FC epilogue: 128000 outputs over 32768 threads (4 iters) ----
    for (unsigned idx = (unsigned)bid * NTHR + tid; idx < BATCH * CLASSES;
         idx += (unsigned)NBLK * NTHR) {
        const int b   = idx / CLASSES;
        const int cls = idx % CLASSES;
        const unsigned short* hrow = h0 + (size_t)b * HID;
        const float* wrow = W_fc + (size_t)cls * HID;
        float acc = 0.f;
        #pragma unroll 4
        for (int k = 0; k < HID; k += 8) {
            bf16x8 hv = *(const bf16x8*)(hrow + k);
            float4 w0 = *(const float4*)(wrow + k);
            float4 w1 = *(const float4*)(wrow + k + 4);
            union { unsigned u; float f; } e;
            float s = 0.f;
            e.u = ((unsigned)(unsigned short)hv[0]) << 16; s += e.f * w0.x;
            e.u = ((unsigned)(unsigned short)hv[1]) << 16; s += e.f * w0.y;
            e.u = ((unsigned)(unsigned short)hv[2]) << 16; s += e.f * w0.z;
            e.u = ((unsigned)(unsigned short)hv[3]) << 16; s += e.f * w0.w;
            e.u = ((unsigned)(unsigned short)hv[4]) << 16; s += e.f * w1.x;
            e.u = ((unsigned)(unsigned short)hv[5]) << 16; s += e.f * w1.y;
            e.u = ((unsigned)(unsigned short)hv[6]) << 16; s += e.f * w1.z;
            e.u = ((unsigned)(unsigned short)hv[7]) << 16; s += e.f * w1.w;
            acc += s;
        }
        out[idx] = acc + b_fc[cls];
    }
}

extern "C" void kernel_launch(void* const* d_in, const int* in_sizes, int n_in,
                              void* d_out, int out_size, void* d_ws, size_t ws_size,
                              hipStream_t stream) {
    const float* x    = (const float*)d_in[0];
    const float* W_ih = (const float*)d_in[1];
    const float* W_hh = (const float*)d_in[2];
    const float* b_ih = (const float*)d_in[3];
    const float* b_hh = (const float*)d_in[4];
    const float* W_fc = (const float*)d_in[5];
    const float* b_fc = (const float*)d_in[6];
    float* out = (float*)d_out;

    unsigned short* h0 = (unsigned short*)d_ws;                      // 256 KB
    unsigned short* h1 = h0 + (size_t)BATCH * HID;                   // 256 KB
    unsigned short* xbf = (unsigned short*)((char*)d_ws + 524288);   // 64 MB opt
    const size_t need_xbf = 524288 + (size_t)SEQ * BATCH * INP * 2;
    int use_xbf = (ws_size >= need_xbf) ? 1 : 0;
    unsigned* flags = (unsigned*)d_out;  // 128 words; overwritten by FC at end

    void* args[] = {&x, &W_ih, &W_hh, &b_ih, &b_hh, &W_fc, &b_fc,
                    &out, &h0, &h1, &xbf, &use_xbf, &flags};
    hipLaunchCooperativeKernel((void*)lstm_fused, dim3(NBLK), dim3(NTHR),
                               args, 0, stream);
}